// Round 11
// baseline (17497.072 us; speedup 1.0000x reference)
//
#include <hip/hip_runtime.h>
#include <cstdint>
#include <cstddef>

#define N_NODES 20000
#define N_EDGES 640000
#define N_GRAPH 64

typedef __attribute__((ext_vector_type(8))) short bf16x8;
typedef __attribute__((ext_vector_type(4))) float f32x4;

// ---------------- math helpers ----------------
__device__ __forceinline__ float sigmoidf_(float x) {
    return 1.0f / (1.0f + __expf(-x));
}
__device__ __forceinline__ float tanhf_(float x) {
    float xc = fminf(fmaxf(x, -9.0f), 9.0f);
    float e = __expf(2.0f * xc);
    return (e - 1.0f) / (e + 1.0f);
}
__device__ __forceinline__ unsigned short f2bf_(float x) {
    unsigned int u = __builtin_bit_cast(unsigned int, x);
    return (unsigned short)((u + 0x7fffu + ((u >> 16) & 1u)) >> 16);
}
__device__ __forceinline__ float sel4_(f32x4 v, bool b1, bool b2) {
    float lo = b1 ? v.y : v.x;      // static regs, runtime mask -> cndmask tree
    float hi = b1 ? v.w : v.z;
    return b2 ? hi : lo;
}

// ---------------- CSR build ----------------
__global__ void count_kernel(const int* __restrict__ dst, int* __restrict__ cnt, int e) {
    int i = blockIdx.x * blockDim.x + threadIdx.x;
    if (i < e) atomicAdd(&cnt[dst[i]], 1);
}

__global__ void scan_kernel(const int* __restrict__ cnt, int* __restrict__ rowstart, int n) {
    __shared__ int buf[1024];
    __shared__ int carry_sh;
    int tid = threadIdx.x;
    if (tid == 0) carry_sh = 0;
    __syncthreads();
    for (int base = 0; base < n; base += 1024) {
        int i = base + tid;
        int v = (i < n) ? cnt[i] : 0;
        buf[tid] = v;
        __syncthreads();
        for (int off = 1; off < 1024; off <<= 1) {
            int t = (tid >= off) ? buf[tid - off] : 0;
            __syncthreads();
            buf[tid] += t;
            __syncthreads();
        }
        int carry = carry_sh;
        if (i < n) rowstart[i] = carry + buf[tid] - v;   // exclusive
        __syncthreads();
        if (tid == 1023) carry_sh = carry + buf[1023];
        __syncthreads();
    }
    if (tid == 0) rowstart[n] = carry_sh;
}

__global__ void dinv_kernel(const int* __restrict__ cnt, float* __restrict__ dinv, int n) {
    int i = blockIdx.x * blockDim.x + threadIdx.x;
    if (i < n) dinv[i] = rsqrtf((float)cnt[i] + 1.0f);   // +1 for self loop; deg >= 1
}

__global__ void fill_kernel(const int* __restrict__ src, const int* __restrict__ dst,
                            const int* __restrict__ rowstart, int* __restrict__ cursor,
                            int* __restrict__ csr_src, int e) {
    int i = blockIdx.x * blockDim.x + threadIdx.x;
    if (i < e) {
        int d = dst[i];
        int pos = rowstart[d] + atomicAdd(&cursor[d], 1);
        csr_src[pos] = src[i];
    }
}

// ---------------- tiled f32 GEMM: C[M,F] = A[M,K] * B (+bias)(relu) ----------------
template <bool BT, bool RELU, bool BIAS>
__global__ void gemm_kernel(const float* __restrict__ A, const float* __restrict__ B,
                            const float* __restrict__ bias, float* __restrict__ C,
                            int M, int K, int F) {
    __shared__ float As[16][65];
    __shared__ float Bs[16][65];
    int bm = blockIdx.x * 64;
    int bn = blockIdx.y * 64;
    int tid = threadIdx.x;                 // 256 threads
    int tm = (tid >> 4) << 2;
    int tn = (tid & 15) << 2;
    float acc[4][4] = {};
    for (int k0 = 0; k0 < K; k0 += 16) {
        {   // A tile: 64 rows x 16 k
            int idx = tid * 4;
            int m = idx >> 4;
            int kk = idx & 15;
            int gm = bm + m;
            float4 v = make_float4(0.f, 0.f, 0.f, 0.f);
            if (gm < M) v = *(const float4*)&A[(size_t)gm * K + k0 + kk];
            As[kk + 0][m] = v.x; As[kk + 1][m] = v.y; As[kk + 2][m] = v.z; As[kk + 3][m] = v.w;
        }
        if (BT) {
            int idx = tid * 4;
            int nn = idx >> 4;
            int kk = idx & 15;
            float4 v = *(const float4*)&B[(size_t)(bn + nn) * K + k0 + kk];
            Bs[kk + 0][nn] = v.x; Bs[kk + 1][nn] = v.y; Bs[kk + 2][nn] = v.z; Bs[kk + 3][nn] = v.w;
        } else {
            int idx = tid * 4;
            int kk = idx >> 6;
            int nn = idx & 63;
            float4 v = *(const float4*)&B[(size_t)(k0 + kk) * F + bn + nn];
            Bs[kk][nn + 0] = v.x; Bs[kk][nn + 1] = v.y; Bs[kk][nn + 2] = v.z; Bs[kk][nn + 3] = v.w;
        }
        __syncthreads();
#pragma unroll
        for (int kk = 0; kk < 16; ++kk) {
            float av[4], bv[4];
#pragma unroll
            for (int i = 0; i < 4; ++i) av[i] = As[kk][tm + i];
#pragma unroll
            for (int j = 0; j < 4; ++j) bv[j] = Bs[kk][tn + j];
#pragma unroll
            for (int i = 0; i < 4; ++i)
#pragma unroll
                for (int j = 0; j < 4; ++j) acc[i][j] += av[i] * bv[j];
        }
        __syncthreads();
    }
#pragma unroll
    for (int i = 0; i < 4; ++i) {
        int gm = bm + tm + i;
        if (gm >= M) continue;
#pragma unroll
        for (int j = 0; j < 4; ++j) {
            float v = acc[i][j];
            if (BIAS) v += bias[bn + tn + j];
            if (RELU) v = fmaxf(v, 0.0f);
            C[(size_t)gm * F + bn + tn + j] = v;
        }
    }
}

// ---------------- GCN aggregation ----------------
__global__ void agg_kernel(const float* __restrict__ H, const int* __restrict__ rowstart,
                           const int* __restrict__ csr_src, const float* __restrict__ dinv,
                           const float* __restrict__ bias, float* __restrict__ OUT, int F) {
    int n = blockIdx.x;
    int f = threadIdx.x;
    float di = dinv[n];
    int s = rowstart[n], e = rowstart[n + 1];
    float acc = di * H[(size_t)n * F + f];   // self loop
    for (int i = s; i < e; ++i) {
        int src = csr_src[i];
        acc += dinv[src] * H[(size_t)src * F + f];
    }
    OUT[(size_t)n * F + f] = fmaxf(bias[f] + di * acc, 0.0f);
}

__global__ void vadd_kernel(const float* __restrict__ a, const float* __restrict__ b,
                            float* __restrict__ o, int n) {
    int i = blockIdx.x * blockDim.x + threadIdx.x;
    if (i < n) o[i] = a[i] + b[i];
}

// ---------------- Whh -> bf16 fragment-order rearrange (4-wave layout) ----------------
// wave w (0..3) owns units [32w,32w+32) x 4 gates = 128 gate rows.
// frag i = (s*2+h)*4 + kc  (s=gate 0..3, h=unit-half 0/1, kc=k-chunk 0..3), i in 0..31.
// lane l: elem j = Whh[128s + 32w + 16h + (l&15)][kc*32 + (l>>4)*8 + j]
// flat at out[(w*32+i)*64 + l]; staged to AGPR a[4i .. 4i+3].
__global__ void wprep_kernel(const float* __restrict__ whh, uint4* __restrict__ out) {
    int tau = blockIdx.x * blockDim.x + threadIdx.x;   // 0..8191
    if (tau >= 8192) return;
    int l  = tau & 63;
    int i  = (tau >> 6) & 31;
    int w  = tau >> 11;
    int kc = i & 3;
    int sh = i >> 2;
    int h  = sh & 1;
    int s  = sh >> 1;
    int grow = 128 * s + 32 * w + 16 * h + (l & 15);
    int kb   = kc * 32 + (l >> 4) * 8;
    const float* src = whh + (size_t)grow * 128 + kb;
    unsigned int hv[8];
#pragma unroll
    for (int j = 0; j < 8; ++j) hv[j] = f2bf_(src[j]);
    uint4 v;
    v.x = hv[0] | (hv[1] << 16);
    v.y = hv[2] | (hv[3] << 16);
    v.z = hv[4] | (hv[5] << 16);
    v.w = hv[6] | (hv[7] << 16);
    out[tau] = v;
}

// ---------------- LSTM: 4 waves, 128 AGPR weights, 1 lgkm-only barrier/step ----------------
#define SF(i, A0, A1, A2, A3) { \
    uint4 q = wfr[(size_t)(w * 32 + (i)) * 64 + l]; \
    asm volatile("v_accvgpr_write_b32 a" #A0 ", %0\n\t" \
                 "v_accvgpr_write_b32 a" #A1 ", %1\n\t" \
                 "v_accvgpr_write_b32 a" #A2 ", %2\n\t" \
                 "v_accvgpr_write_b32 a" #A3 ", %3" \
                 :: "v"(q.x), "v"(q.y), "v"(q.z), "v"(q.w) \
                 : "a" #A0, "a" #A1, "a" #A2, "a" #A3); }

// One LSTM step. X<s><h> (8 regs) enter as xg C-in (destroyed) and are reloaded with
// step N+2's xg (counted vmcnt keeps them in flight across the lgkm-only barrier).
#define LSTM_STEP(N, X00, X01, X10, X11, X20, X21, X30, X31, RD, WR) do { \
    bf16x8 b0 = *(const bf16x8*)&h_bf[RD][ 0 + lg * 8]; \
    bf16x8 b1 = *(const bf16x8*)&h_bf[RD][32 + lg * 8]; \
    bf16x8 b2 = *(const bf16x8*)&h_bf[RD][64 + lg * 8]; \
    bf16x8 b3 = *(const bf16x8*)&h_bf[RD][96 + lg * 8]; \
    asm volatile( \
        "s_nop 1\n\t" \
        "v_mfma_f32_16x16x32_bf16 %0, a[0:3],     %8, %0\n\t" \
        "v_mfma_f32_16x16x32_bf16 %1, a[16:19],   %8, %1\n\t" \
        "v_mfma_f32_16x16x32_bf16 %2, a[32:35],   %8, %2\n\t" \
        "v_mfma_f32_16x16x32_bf16 %3, a[48:51],   %8, %3\n\t" \
        "v_mfma_f32_16x16x32_bf16 %4, a[64:67],   %8, %4\n\t" \
        "v_mfma_f32_16x16x32_bf16 %5, a[80:83],   %8, %5\n\t" \
        "v_mfma_f32_16x16x32_bf16 %6, a[96:99],   %8, %6\n\t" \
        "v_mfma_f32_16x16x32_bf16 %7, a[112:115], %8, %7" \
        : "+v"(X00), "+v"(X01), "+v"(X10), "+v"(X11), \
          "+v"(X20), "+v"(X21), "+v"(X30), "+v"(X31) : "v"(b0)); \
    asm volatile( \
        "v_mfma_f32_16x16x32_bf16 %0, a[4:7],     %8, %0\n\t" \
        "v_mfma_f32_16x16x32_bf16 %1, a[20:23],   %8, %1\n\t" \
        "v_mfma_f32_16x16x32_bf16 %2, a[36:39],   %8, %2\n\t" \
        "v_mfma_f32_16x16x32_bf16 %3, a[52:55],   %8, %3\n\t" \
        "v_mfma_f32_16x16x32_bf16 %4, a[68:71],   %8, %4\n\t" \
        "v_mfma_f32_16x16x32_bf16 %5, a[84:87],   %8, %5\n\t" \
        "v_mfma_f32_16x16x32_bf16 %6, a[100:103], %8, %6\n\t" \
        "v_mfma_f32_16x16x32_bf16 %7, a[116:119], %8, %7" \
        : "+v"(X00), "+v"(X01), "+v"(X10), "+v"(X11), \
          "+v"(X20), "+v"(X21), "+v"(X30), "+v"(X31) : "v"(b1)); \
    asm volatile( \
        "v_mfma_f32_16x16x32_bf16 %0, a[8:11],    %8, %0\n\t" \
        "v_mfma_f32_16x16x32_bf16 %1, a[24:27],   %8, %1\n\t" \
        "v_mfma_f32_16x16x32_bf16 %2, a[40:43],   %8, %2\n\t" \
        "v_mfma_f32_16x16x32_bf16 %3, a[56:59],   %8, %3\n\t" \
        "v_mfma_f32_16x16x32_bf16 %4, a[72:75],   %8, %4\n\t" \
        "v_mfma_f32_16x16x32_bf16 %5, a[88:91],   %8, %5\n\t" \
        "v_mfma_f32_16x16x32_bf16 %6, a[104:107], %8, %6\n\t" \
        "v_mfma_f32_16x16x32_bf16 %7, a[120:123], %8, %7" \
        : "+v"(X00), "+v"(X01), "+v"(X10), "+v"(X11), \
          "+v"(X20), "+v"(X21), "+v"(X30), "+v"(X31) : "v"(b2)); \
    asm volatile( \
        "v_mfma_f32_16x16x32_bf16 %0, a[12:15],   %8, %0\n\t" \
        "v_mfma_f32_16x16x32_bf16 %1, a[28:31],   %8, %1\n\t" \
        "v_mfma_f32_16x16x32_bf16 %2, a[44:47],   %8, %2\n\t" \
        "v_mfma_f32_16x16x32_bf16 %3, a[60:63],   %8, %3\n\t" \
        "v_mfma_f32_16x16x32_bf16 %4, a[76:79],   %8, %4\n\t" \
        "v_mfma_f32_16x16x32_bf16 %5, a[92:95],   %8, %5\n\t" \
        "v_mfma_f32_16x16x32_bf16 %6, a[108:111], %8, %6\n\t" \
        "v_mfma_f32_16x16x32_bf16 %7, a[124:127], %8, %7\n\t" \
        "s_nop 7\n\t" \
        "s_nop 7" \
        : "+v"(X00), "+v"(X01), "+v"(X10), "+v"(X11), \
          "+v"(X20), "+v"(X21), "+v"(X30), "+v"(X31) : "v"(b3)); \
    /* lane: gates for unit u0 (h=0) and u1 = u0+16 (h=1), replicated over cols */ \
    float gi0 = sel4_(X00, s1m, s2m), gi1 = sel4_(X01, s1m, s2m); \
    float gf0 = sel4_(X10, s1m, s2m), gf1 = sel4_(X11, s1m, s2m); \
    float gg0 = sel4_(X20, s1m, s2m), gg1 = sel4_(X21, s1m, s2m); \
    float go0 = sel4_(X30, s1m, s2m), go1 = sel4_(X31, s1m, s2m); \
    { int np = ((N) + 2 < steps) ? (N) + 2 : (N); \
      const float* xp = xg + (size_t)np * 512 + xbase; \
      X00 = *(const f32x4*)(xp);       X01 = *(const f32x4*)(xp + 16); \
      X10 = *(const f32x4*)(xp + 128); X11 = *(const f32x4*)(xp + 144); \
      X20 = *(const f32x4*)(xp + 256); X21 = *(const f32x4*)(xp + 272); \
      X30 = *(const f32x4*)(xp + 384); X31 = *(const f32x4*)(xp + 400); } \
    float iv0 = sigmoidf_(gi0), iv1 = sigmoidf_(gi1); \
    float fv0 = sigmoidf_(gf0), fv1 = sigmoidf_(gf1); \
    float gv0 = tanhf_(gg0),    gv1 = tanhf_(gg1); \
    float ov0 = sigmoidf_(go0), ov1 = sigmoidf_(go1); \
    c0 = fv0 * c0 + iv0 * gv0; \
    c1 = fv1 * c1 + iv1 * gv1; \
    float hn0 = ov0 * tanhf_(c0); \
    float hn1 = ov1 * tanhf_(c1); \
    if (wrlane) { h_bf[WR][u0] = f2bf_(hn0); h_bf[WR][u1] = f2bf_(hn1); } \
    while ((N) == bnext) { \
        if (wrlane) { poolsum[gidx * 128 + u0] = pacc0; poolsum[gidx * 128 + u1] = pacc1; } \
        pacc0 = 0.0f; pacc1 = 0.0f; ++gidx; bnext = bnd_s[gidx + 1]; \
    } \
    pacc0 += hn0; pacc1 += hn1; \
    asm volatile("s_waitcnt lgkmcnt(0)\n\ts_barrier" ::: "memory"); \
} while (0)

__global__ __launch_bounds__(256)
__attribute__((amdgpu_waves_per_eu(1, 1)))
void lstm_mfma_kernel(const float* __restrict__ xg, const uint4* __restrict__ wfr,
                      const int* __restrict__ batch, float* __restrict__ poolsum, int steps) {
    __shared__ __align__(16) unsigned short h_bf[2][128];
    __shared__ int bnd_s[65];
    const int t = threadIdx.x;
    const int w = t >> 6;                 // wave 0..3 -> units [32w, 32w+32)
    const int l = t & 63;
    const int lg = l >> 4;
    const bool s1m = (l & 1) != 0;
    const bool s2m = (l & 2) != 0;
    const bool wrlane = (l & 15) < 4;     // one writer copy per unit
    const int u0 = 32 * w + 4 * lg + (l & 3);     // half-0 unit
    const int u1 = u0 + 16;                        // half-1 unit
    const int xbase = 32 * w + 4 * lg;

    // stage Whh into AGPRs a0..a127 once
    SF(0, 0, 1, 2, 3)       SF(1, 4, 5, 6, 7)       SF(2, 8, 9, 10, 11)     SF(3, 12, 13, 14, 15)
    SF(4, 16, 17, 18, 19)   SF(5, 20, 21, 22, 23)   SF(6, 24, 25, 26, 27)   SF(7, 28, 29, 30, 31)
    SF(8, 32, 33, 34, 35)   SF(9, 36, 37, 38, 39)   SF(10, 40, 41, 42, 43)  SF(11, 44, 45, 46, 47)
    SF(12, 48, 49, 50, 51)  SF(13, 52, 53, 54, 55)  SF(14, 56, 57, 58, 59)  SF(15, 60, 61, 62, 63)
    SF(16, 64, 65, 66, 67)  SF(17, 68, 69, 70, 71)  SF(18, 72, 73, 74, 75)  SF(19, 76, 77, 78, 79)
    SF(20, 80, 81, 82, 83)  SF(21, 84, 85, 86, 87)  SF(22, 88, 89, 90, 91)  SF(23, 92, 93, 94, 95)
    SF(24, 96, 97, 98, 99)  SF(25, 100, 101, 102, 103) SF(26, 104, 105, 106, 107) SF(27, 108, 109, 110, 111)
    SF(28, 112, 113, 114, 115) SF(29, 116, 117, 118, 119) SF(30, 120, 121, 122, 123) SF(31, 124, 125, 126, 127)

    if (t < 128) h_bf[0][t] = 0;
    if (t <= 64) {                         // one-time graph-boundary table
        int lo = 0, hi = steps;
        while (lo < hi) { int m = (lo + hi) >> 1; if (batch[m] < t) lo = m + 1; else hi = m; }
        bnd_s[t] = lo;
    }
    float c0 = 0.0f, c1 = 0.0f, pacc0 = 0.0f, pacc1 = 0.0f;

    // 2-deep xg pipeline: xa = step 0, xb = step 1 (8 f32x4 each)
    const float* x0p = xg + xbase;
    f32x4 xa00 = *(const f32x4*)(x0p);       f32x4 xa01 = *(const f32x4*)(x0p + 16);
    f32x4 xa10 = *(const f32x4*)(x0p + 128); f32x4 xa11 = *(const f32x4*)(x0p + 144);
    f32x4 xa20 = *(const f32x4*)(x0p + 256); f32x4 xa21 = *(const f32x4*)(x0p + 272);
    f32x4 xa30 = *(const f32x4*)(x0p + 384); f32x4 xa31 = *(const f32x4*)(x0p + 400);
    const float* x1p = xg + 512 + xbase;
    f32x4 xb00 = *(const f32x4*)(x1p);       f32x4 xb01 = *(const f32x4*)(x1p + 16);
    f32x4 xb10 = *(const f32x4*)(x1p + 128); f32x4 xb11 = *(const f32x4*)(x1p + 144);
    f32x4 xb20 = *(const f32x4*)(x1p + 256); f32x4 xb21 = *(const f32x4*)(x1p + 272);
    f32x4 xb30 = *(const f32x4*)(x1p + 384); f32x4 xb31 = *(const f32x4*)(x1p + 400);
    __syncthreads();                       // init barrier (full drain OK, once)
    int gidx = 0, bnext = bnd_s[1];

    for (int n = 0; n < steps; n += 2) {   // steps even (20000)
        LSTM_STEP(n,     xa00, xa01, xa10, xa11, xa20, xa21, xa30, xa31, 0, 1);
        LSTM_STEP(n + 1, xb00, xb01, xb10, xb11, xb20, xb21, xb30, xb31, 1, 0);
    }
    if (wrlane) { poolsum[gidx * 128 + u0] = pacc0; poolsum[gidx * 128 + u1] = pacc1; }
}

// ---------------- head (computes counts itself via binary search) ----------------
__global__ void head_kernel(const float* __restrict__ poolsum, const int* __restrict__ batch,
                            int nn,
                            const float* __restrict__ attn_in_w, const float* __restrict__ attn_in_b,
                            const float* __restrict__ attn_out_w, const float* __restrict__ attn_out_b,
                            const float* __restrict__ l1w, const float* __restrict__ l1b,
                            const float* __restrict__ l2w, const float* __restrict__ l2b,
                            float* __restrict__ out) {
    __shared__ float hbar[128], tv[128], pl[128], z1[64], lg[2];
    int g = blockIdx.x, t = threadIdx.x;   // 128 threads
    int lo = 0, hi = nn;
    while (lo < hi) { int m = (lo + hi) >> 1; if (batch[m] < g) lo = m + 1; else hi = m; }
    int s0 = lo;
    lo = 0; hi = nn;
    while (lo < hi) { int m = (lo + hi) >> 1; if (batch[m] <= g) lo = m + 1; else hi = m; }
    int e0 = lo;
    float cntv = fmaxf((float)(e0 - s0), 1.0f);
    hbar[t] = poolsum[g * 128 + t] / cntv;
    __syncthreads();
    float a = attn_in_b[256 + t];
    for (int k = 0; k < 128; ++k) a += attn_in_w[(256 + t) * 128 + k] * hbar[k];
    tv[t] = a;
    __syncthreads();
    float pv = attn_out_b[t];
    for (int k = 0; k < 128; ++k) pv += attn_out_w[t * 128 + k] * tv[k];
    pl[t] = pv;
    __syncthreads();
    if (t < 64) {
        float z = l1b[t];
        for (int k = 0; k < 128; ++k) z += l1w[t * 128 + k] * pl[k];
        z1[t] = fmaxf(z, 0.0f);
    }
    __syncthreads();
    if (t < 2) {
        float lv = l2b[t];
        for (int k = 0; k < 64; ++k) lv += l2w[t * 64 + k] * z1[k];
        lg[t] = lv;
    }
    __syncthreads();
    if (t == 0) {
        float m = fmaxf(lg[0], lg[1]);
        float ls = m + logf(__expf(lg[0] - m) + __expf(lg[1] - m));
        out[g * 2 + 0] = lg[0] - ls;
        out[g * 2 + 1] = lg[1] - ls;
    }
}

// ---------------- launch ----------------
extern "C" void kernel_launch(void* const* d_in, const int* in_sizes, int n_in,
                              void* d_out, int out_size, void* d_ws, size_t ws_size,
                              hipStream_t stream) {
    const float* x          = (const float*)d_in[0];
    const int*   ei         = (const int*)d_in[1];
    const int*   batch      = (const int*)d_in[2];
    const float* w1 = (const float*)d_in[3];  const float* b1 = (const float*)d_in[4];
    const float* w2 = (const float*)d_in[5];  const float* b2 = (const float*)d_in[6];
    const float* w3 = (const float*)d_in[7];  const float* b3 = (const float*)d_in[8];
    const float* w4 = (const float*)d_in[9];  const float* b4 = (const float*)d_in[10];
    const float* wih = (const float*)d_in[11]; const float* whh = (const float*)d_in[12];
    const float* bih = (const float*)d_in[13]; const float* bhh = (const float*)d_in[14];
    const float* attn_in_w  = (const float*)d_in[15]; const float* attn_in_b  = (const float*)d_in[16];
    const float* attn_out_w = (const float*)d_in[17]; const float* attn_out_b = (const float*)d_in[18];
    const float* l1w = (const float*)d_in[19]; const float* l1b = (const float*)d_in[20];
    const float* l2w = (const float*)d_in[21]; const float* l2b = (const float*)d_in[22];
    float* out = (float*)d_out;

    char* p = (char*)d_ws;
    auto alloc = [&](size_t bytes) {
        char* r = p;
        p += (bytes + 255) & ~(size_t)255;
        return r;
    };
    int*   cnt      = (int*)alloc((size_t)N_NODES * 4);
    int*   cursor   = (int*)alloc((size_t)N_NODES * 4);
    int*   rowstart = (int*)alloc((size_t)(N_NODES + 1) * 4);
    float* dinv     = (float*)alloc((size_t)N_NODES * 4);
    int*   csr      = (int*)alloc((size_t)N_EDGES * 4);
    float* bsum     = (float*)alloc(512 * 4);
    float* poolsum  = (float*)alloc((size_t)N_GRAPH * 128 * 4);
    uint4* wfrag    = (uint4*)alloc((size_t)8192 * 16);   // 128 KB bf16 Whh frags
    float* bufA     = (float*)alloc((size_t)N_NODES * 256 * 4);
    float* bufB     = (float*)alloc((size_t)N_NODES * 256 * 4);
    float* xg       = (float*)alloc((size_t)N_NODES * 512 * 4);

    hipMemsetAsync(cnt, 0, (size_t)N_NODES * 4, stream);
    hipMemsetAsync(cursor, 0, (size_t)N_NODES * 4, stream);
    hipMemsetAsync(poolsum, 0, (size_t)N_GRAPH * 128 * 4, stream);   // empty-graph safety

    const int* srcp = ei;
    const int* dstp = ei + N_EDGES;

    int eb = (N_EDGES + 255) / 256;
    int nb = (N_NODES + 255) / 256;
    count_kernel<<<eb, 256, 0, stream>>>(dstp, cnt, N_EDGES);
    scan_kernel<<<1, 1024, 0, stream>>>(cnt, rowstart, N_NODES);
    dinv_kernel<<<nb, 256, 0, stream>>>(cnt, dinv, N_NODES);
    fill_kernel<<<eb, 256, 0, stream>>>(srcp, dstp, rowstart, cursor, csr, N_EDGES);
    wprep_kernel<<<32, 256, 0, stream>>>(whh, wfrag);

    int mg = (N_NODES + 63) / 64;   // 313
    gemm_kernel<false, false, false><<<dim3(mg, 1), 256, 0, stream>>>(x, w1, nullptr, bufA, N_NODES, 128, 64);
    agg_kernel<<<N_NODES, 64, 0, stream>>>(bufA, rowstart, csr, dinv, b1, bufB, 64);
    gemm_kernel<false, false, false><<<dim3(mg, 1), 256, 0, stream>>>(bufB, w2, nullptr, bufA, N_NODES, 64, 64);
    agg_kernel<<<N_NODES, 64, 0, stream>>>(bufA, rowstart, csr, dinv, b2, bufB, 64);
    gemm_kernel<false, false, false><<<dim3(mg, 2), 256, 0, stream>>>(bufB, w3, nullptr, bufA, N_NODES, 64, 128);
    agg_kernel<<<N_NODES, 128, 0, stream>>>(bufA, rowstart, csr, dinv, b3, bufB, 128);
    gemm_kernel<false, false, false><<<dim3(mg, 4), 256, 0, stream>>>(bufB, w4, nullptr, bufA, N_NODES, 128, 256);
    agg_kernel<<<N_NODES, 256, 0, stream>>>(bufA, rowstart, csr, dinv, b4, bufB, 256);

    // xg = h4 @ wih^T + (bih + bhh)
    vadd_kernel<<<2, 256, 0, stream>>>(bih, bhh, bsum, 512);
    gemm_kernel<true, false, true><<<dim3(mg, 8), 256, 0, stream>>>(bufB, wih, bsum, xg, N_NODES, 256, 512);

    // sequential LSTM: 4 waves, AGPR weights, lgkm-only barrier, in-register gates
    lstm_mfma_kernel<<<1, 256, 0, stream>>>(xg, (const uint4*)wfrag, batch, poolsum, N_NODES);

    // head
    head_kernel<<<N_GRAPH, 128, 0, stream>>>(poolsum, batch, N_NODES,
                                             attn_in_w, attn_in_b, attn_out_w, attn_out_b,
                                             l1w, l1b, l2w, l2b, out);
}

// Round 12
// 13274.939 us; speedup vs baseline: 1.3181x; 1.3181x over previous
//
#include <hip/hip_runtime.h>
#include <cstdint>
#include <cstddef>

#define N_NODES 20000
#define N_EDGES 640000
#define N_GRAPH 64

typedef __attribute__((ext_vector_type(8))) short bf16x8;
typedef __attribute__((ext_vector_type(4))) float f32x4;

// ---------------- math helpers ----------------
__device__ __forceinline__ float sigmoidf_(float x) {
    return 1.0f / (1.0f + __expf(-x));
}
__device__ __forceinline__ float tanhf_(float x) {
    float xc = fminf(fmaxf(x, -9.0f), 9.0f);
    float e = __expf(2.0f * xc);
    return (e - 1.0f) / (e + 1.0f);
}
__device__ __forceinline__ unsigned short f2bf_(float x) {
    unsigned int u = __builtin_bit_cast(unsigned int, x);
    return (unsigned short)((u + 0x7fffu + ((u >> 16) & 1u)) >> 16);
}
__device__ __forceinline__ float sel4_(f32x4 v, bool b1, bool b2) {
    float lo = b1 ? v.y : v.x;      // static regs, runtime mask -> cndmask tree
    float hi = b1 ? v.w : v.z;
    return b2 ? hi : lo;
}

// ---------------- CSR build ----------------
__global__ void count_kernel(const int* __restrict__ dst, int* __restrict__ cnt, int e) {
    int i = blockIdx.x * blockDim.x + threadIdx.x;
    if (i < e) atomicAdd(&cnt[dst[i]], 1);
}

__global__ void scan_kernel(const int* __restrict__ cnt, int* __restrict__ rowstart, int n) {
    __shared__ int buf[1024];
    __shared__ int carry_sh;
    int tid = threadIdx.x;
    if (tid == 0) carry_sh = 0;
    __syncthreads();
    for (int base = 0; base < n; base += 1024) {
        int i = base + tid;
        int v = (i < n) ? cnt[i] : 0;
        buf[tid] = v;
        __syncthreads();
        for (int off = 1; off < 1024; off <<= 1) {
            int t = (tid >= off) ? buf[tid - off] : 0;
            __syncthreads();
            buf[tid] += t;
            __syncthreads();
        }
        int carry = carry_sh;
        if (i < n) rowstart[i] = carry + buf[tid] - v;   // exclusive
        __syncthreads();
        if (tid == 1023) carry_sh = carry + buf[1023];
        __syncthreads();
    }
    if (tid == 0) rowstart[n] = carry_sh;
}

__global__ void dinv_kernel(const int* __restrict__ cnt, float* __restrict__ dinv, int n) {
    int i = blockIdx.x * blockDim.x + threadIdx.x;
    if (i < n) dinv[i] = rsqrtf((float)cnt[i] + 1.0f);   // +1 for self loop; deg >= 1
}

__global__ void fill_kernel(const int* __restrict__ src, const int* __restrict__ dst,
                            const int* __restrict__ rowstart, int* __restrict__ cursor,
                            int* __restrict__ csr_src, int e) {
    int i = blockIdx.x * blockDim.x + threadIdx.x;
    if (i < e) {
        int d = dst[i];
        int pos = rowstart[d] + atomicAdd(&cursor[d], 1);
        csr_src[pos] = src[i];
    }
}

// ---------------- tiled f32 GEMM: C[M,F] = A[M,K] * B (+bias)(relu) ----------------
template <bool BT, bool RELU, bool BIAS>
__global__ void gemm_kernel(const float* __restrict__ A, const float* __restrict__ B,
                            const float* __restrict__ bias, float* __restrict__ C,
                            int M, int K, int F) {
    __shared__ float As[16][65];
    __shared__ float Bs[16][65];
    int bm = blockIdx.x * 64;
    int bn = blockIdx.y * 64;
    int tid = threadIdx.x;                 // 256 threads
    int tm = (tid >> 4) << 2;
    int tn = (tid & 15) << 2;
    float acc[4][4] = {};
    for (int k0 = 0; k0 < K; k0 += 16) {
        {   // A tile: 64 rows x 16 k
            int idx = tid * 4;
            int m = idx >> 4;
            int kk = idx & 15;
            int gm = bm + m;
            float4 v = make_float4(0.f, 0.f, 0.f, 0.f);
            if (gm < M) v = *(const float4*)&A[(size_t)gm * K + k0 + kk];
            As[kk + 0][m] = v.x; As[kk + 1][m] = v.y; As[kk + 2][m] = v.z; As[kk + 3][m] = v.w;
        }
        if (BT) {
            int idx = tid * 4;
            int nn = idx >> 4;
            int kk = idx & 15;
            float4 v = *(const float4*)&B[(size_t)(bn + nn) * K + k0 + kk];
            Bs[kk + 0][nn] = v.x; Bs[kk + 1][nn] = v.y; Bs[kk + 2][nn] = v.z; Bs[kk + 3][nn] = v.w;
        } else {
            int idx = tid * 4;
            int kk = idx >> 6;
            int nn = idx & 63;
            float4 v = *(const float4*)&B[(size_t)(k0 + kk) * F + bn + nn];
            Bs[kk][nn + 0] = v.x; Bs[kk][nn + 1] = v.y; Bs[kk][nn + 2] = v.z; Bs[kk][nn + 3] = v.w;
        }
        __syncthreads();
#pragma unroll
        for (int kk = 0; kk < 16; ++kk) {
            float av[4], bv[4];
#pragma unroll
            for (int i = 0; i < 4; ++i) av[i] = As[kk][tm + i];
#pragma unroll
            for (int j = 0; j < 4; ++j) bv[j] = Bs[kk][tn + j];
#pragma unroll
            for (int i = 0; i < 4; ++i)
#pragma unroll
                for (int j = 0; j < 4; ++j) acc[i][j] += av[i] * bv[j];
        }
        __syncthreads();
    }
#pragma unroll
    for (int i = 0; i < 4; ++i) {
        int gm = bm + tm + i;
        if (gm >= M) continue;
#pragma unroll
        for (int j = 0; j < 4; ++j) {
            float v = acc[i][j];
            if (BIAS) v += bias[bn + tn + j];
            if (RELU) v = fmaxf(v, 0.0f);
            C[(size_t)gm * F + bn + tn + j] = v;
        }
    }
}

// ---------------- GCN aggregation ----------------
__global__ void agg_kernel(const float* __restrict__ H, const int* __restrict__ rowstart,
                           const int* __restrict__ csr_src, const float* __restrict__ dinv,
                           const float* __restrict__ bias, float* __restrict__ OUT, int F) {
    int n = blockIdx.x;
    int f = threadIdx.x;
    float di = dinv[n];
    int s = rowstart[n], e = rowstart[n + 1];
    float acc = di * H[(size_t)n * F + f];   // self loop
    for (int i = s; i < e; ++i) {
        int src = csr_src[i];
        acc += dinv[src] * H[(size_t)src * F + f];
    }
    OUT[(size_t)n * F + f] = fmaxf(bias[f] + di * acc, 0.0f);
}

__global__ void vadd_kernel(const float* __restrict__ a, const float* __restrict__ b,
                            float* __restrict__ o, int n) {
    int i = blockIdx.x * blockDim.x + threadIdx.x;
    if (i < n) o[i] = a[i] + b[i];
}

// ---------------- Whh -> bf16 fragment-order rearrange (gate-per-subtile layout) ----------------
// wave w (0..7) owns hidden units [16w,16w+16); frag i = s*4+kc, s = GATE (0=i,1=f,2=g,3=o),
// kc = k-chunk. lane l: elem j = Whh[128s + 16w + (l&15)][kc*32 + (l>>4)*8 + j]
// flat at out[(w*16+i)*64 + l].
__global__ void wprep_kernel(const float* __restrict__ whh, uint4* __restrict__ out) {
    int tau = blockIdx.x * blockDim.x + threadIdx.x;   // 0..8191
    if (tau >= 8192) return;
    int l  = tau & 63;
    int f  = (tau >> 6) & 15;
    int w  = tau >> 10;
    int s  = f >> 2, kc = f & 3;
    int grow = 128 * s + 16 * w + (l & 15);
    int kb   = kc * 32 + (l >> 4) * 8;
    const float* src = whh + (size_t)grow * 128 + kb;
    unsigned int h[8];
#pragma unroll
    for (int j = 0; j < 8; ++j) h[j] = f2bf_(src[j]);
    uint4 v;
    v.x = h[0] | (h[1] << 16);
    v.y = h[2] | (h[3] << 16);
    v.z = h[4] | (h[5] << 16);
    v.w = h[6] | (h[7] << 16);
    out[tau] = v;
}

// ---------------- LSTM: r9 structure + pooling deferred into the ds_read shadow ----------------
#define SF(i, A0, A1, A2, A3) { \
    uint4 q = wfr[(size_t)(w * 16 + (i)) * 64 + l]; \
    asm volatile("v_accvgpr_write_b32 a" #A0 ", %0\n\t" \
                 "v_accvgpr_write_b32 a" #A1 ", %1\n\t" \
                 "v_accvgpr_write_b32 a" #A2 ", %2\n\t" \
                 "v_accvgpr_write_b32 a" #A3 ", %3" \
                 :: "v"(q.x), "v"(q.y), "v"(q.z), "v"(q.w) \
                 : "a" #A0, "a" #A1, "a" #A2, "a" #A3); }

// One LSTM step. X0..X3 enter as xg C-in (destroyed by MFMA), then are reloaded with
// step N+2's xg (loads stay in flight across the lgkm-only barrier -- no vmcnt drain).
// Pooling for step N-1 (hprev) executes between the ds_read issue and the MFMA wait,
// i.e. under the ~120-cycle LDS latency shadow instead of on the pre-barrier tail.
#define LSTM_STEP(N, X0, X1, X2, X3, RD, WR) do { \
    bf16x8 b0 = *(const bf16x8*)&h_bf[RD][ 0 + lg * 8]; \
    bf16x8 b1 = *(const bf16x8*)&h_bf[RD][32 + lg * 8]; \
    bf16x8 b2 = *(const bf16x8*)&h_bf[RD][64 + lg * 8]; \
    bf16x8 b3 = *(const bf16x8*)&h_bf[RD][96 + lg * 8]; \
    while (pn == bnext) {                 /* graph boundary at step N-1 (rare) */ \
        if (wrlane) poolsum[gidx * 128 + uidx] = pacc; \
        pacc = 0.0f; ++gidx; bnext = bnd_s[gidx + 1]; \
    } \
    pacc += hprev;                        /* accumulate h(N-1) in the shadow */ \
    pn = (N); \
    asm volatile( \
        "s_nop 1\n\t" \
        "v_mfma_f32_16x16x32_bf16 %0, a[0:3],   %4, %0\n\t" \
        "v_mfma_f32_16x16x32_bf16 %1, a[16:19], %4, %1\n\t" \
        "v_mfma_f32_16x16x32_bf16 %2, a[32:35], %4, %2\n\t" \
        "v_mfma_f32_16x16x32_bf16 %3, a[48:51], %4, %3" \
        : "+v"(X0), "+v"(X1), "+v"(X2), "+v"(X3) : "v"(b0)); \
    asm volatile( \
        "v_mfma_f32_16x16x32_bf16 %0, a[4:7],   %4, %0\n\t" \
        "v_mfma_f32_16x16x32_bf16 %1, a[20:23], %4, %1\n\t" \
        "v_mfma_f32_16x16x32_bf16 %2, a[36:39], %4, %2\n\t" \
        "v_mfma_f32_16x16x32_bf16 %3, a[52:55], %4, %3" \
        : "+v"(X0), "+v"(X1), "+v"(X2), "+v"(X3) : "v"(b1)); \
    asm volatile( \
        "v_mfma_f32_16x16x32_bf16 %0, a[8:11],  %4, %0\n\t" \
        "v_mfma_f32_16x16x32_bf16 %1, a[24:27], %4, %1\n\t" \
        "v_mfma_f32_16x16x32_bf16 %2, a[40:43], %4, %2\n\t" \
        "v_mfma_f32_16x16x32_bf16 %3, a[56:59], %4, %3" \
        : "+v"(X0), "+v"(X1), "+v"(X2), "+v"(X3) : "v"(b2)); \
    asm volatile( \
        "v_mfma_f32_16x16x32_bf16 %0, a[12:15], %4, %0\n\t" \
        "v_mfma_f32_16x16x32_bf16 %1, a[28:31], %4, %1\n\t" \
        "v_mfma_f32_16x16x32_bf16 %2, a[44:47], %4, %2\n\t" \
        "v_mfma_f32_16x16x32_bf16 %3, a[60:63], %4, %3\n\t" \
        "s_nop 7\n\t" \
        "s_nop 7" \
        : "+v"(X0), "+v"(X1), "+v"(X2), "+v"(X3) : "v"(b3)); \
    /* every lane holds gates i,f,g,o for unit 16w+4lg+(l&3), cols replicated */ \
    float gi = sel4_(X0, s1m, s2m); \
    float gf = sel4_(X1, s1m, s2m); \
    float gG = sel4_(X2, s1m, s2m); \
    float go = sel4_(X3, s1m, s2m); \
    { int np = ((N) + 2 < steps) ? (N) + 2 : (N); \
      const float* xp = xg + (size_t)np * 512 + xoff; \
      X0 = *(const f32x4*)(xp); \
      X1 = *(const f32x4*)(xp + 128); \
      X2 = *(const f32x4*)(xp + 256); \
      X3 = *(const f32x4*)(xp + 384); } \
    float iv = sigmoidf_(gi); \
    float fv = sigmoidf_(gf); \
    float gv = tanhf_(gG); \
    float ov = sigmoidf_(go); \
    c = fv * c + iv * gv; \
    float hn = ov * tanhf_(c); \
    if (wrlane) h_bf[WR][uidx] = f2bf_(hn); \
    hprev = hn; \
    asm volatile("s_waitcnt lgkmcnt(0)\n\ts_barrier" ::: "memory"); \
} while (0)

__global__ __launch_bounds__(512)
__attribute__((amdgpu_waves_per_eu(2, 2)))
void lstm_mfma_kernel(const float* __restrict__ xg, const uint4* __restrict__ wfr,
                      const int* __restrict__ batch, float* __restrict__ poolsum, int steps) {
    __shared__ __align__(16) unsigned short h_bf[2][128];
    __shared__ int bnd_s[65];
    const int t = threadIdx.x;
    const int w = t >> 6;                 // wave 0..7 -> hidden units [16w, 16w+16)
    const int l = t & 63;
    const int lg = l >> 4;
    const bool s1m = (l & 1) != 0;
    const bool s2m = (l & 2) != 0;
    const bool wrlane = (l & 15) < 4;     // 16 writer lanes per wave
    const int uidx = 16 * w + 4 * lg + (l & 3);   // this lane's hidden unit
    const int xoff = 16 * w + 4 * lg;

    // stage Whh into AGPRs once
    SF(0, 0, 1, 2, 3)     SF(1, 4, 5, 6, 7)     SF(2, 8, 9, 10, 11)    SF(3, 12, 13, 14, 15)
    SF(4, 16, 17, 18, 19) SF(5, 20, 21, 22, 23) SF(6, 24, 25, 26, 27)  SF(7, 28, 29, 30, 31)
    SF(8, 32, 33, 34, 35) SF(9, 36, 37, 38, 39) SF(10, 40, 41, 42, 43) SF(11, 44, 45, 46, 47)
    SF(12, 48, 49, 50, 51) SF(13, 52, 53, 54, 55) SF(14, 56, 57, 58, 59) SF(15, 60, 61, 62, 63)

    if (t < 128) h_bf[0][t] = 0;
    if (t <= 64) {                         // one-time graph-boundary table
        int lo = 0, hi = steps;
        while (lo < hi) { int m = (lo + hi) >> 1; if (batch[m] < t) lo = m + 1; else hi = m; }
        bnd_s[t] = lo;
    }
    float c = 0.0f, pacc = 0.0f, hprev = 0.0f;
    int pn = -1;                           // previous step index (deferred pooling)

    // 2-deep xg pipeline: xa = step 0, xb = step 1
    const float* x0p = xg + xoff;
    f32x4 xa0 = *(const f32x4*)(x0p);
    f32x4 xa1 = *(const f32x4*)(x0p + 128);
    f32x4 xa2 = *(const f32x4*)(x0p + 256);
    f32x4 xa3 = *(const f32x4*)(x0p + 384);
    const float* x1p = xg + 512 + xoff;
    f32x4 xb0 = *(const f32x4*)(x1p);
    f32x4 xb1 = *(const f32x4*)(x1p + 128);
    f32x4 xb2 = *(const f32x4*)(x1p + 256);
    f32x4 xb3 = *(const f32x4*)(x1p + 384);
    __syncthreads();                       // init barrier (full drain OK, once)
    int gidx = 0, bnext = bnd_s[1];

    for (int n = 0; n < steps; n += 2) {   // steps even (20000)
        LSTM_STEP(n,     xa0, xa1, xa2, xa3, 0, 1);
        LSTM_STEP(n + 1, xb0, xb1, xb2, xb3, 1, 0);
    }
    // drain deferred pooling for step steps-1
    while (pn == bnext) {
        if (wrlane) poolsum[gidx * 128 + uidx] = pacc;
        pacc = 0.0f; ++gidx; bnext = bnd_s[gidx + 1];
    }
    pacc += hprev;
    if (wrlane) poolsum[gidx * 128 + uidx] = pacc;
}

// ---------------- head (computes counts itself via binary search) ----------------
__global__ void head_kernel(const float* __restrict__ poolsum, const int* __restrict__ batch,
                            int nn,
                            const float* __restrict__ attn_in_w, const float* __restrict__ attn_in_b,
                            const float* __restrict__ attn_out_w, const float* __restrict__ attn_out_b,
                            const float* __restrict__ l1w, const float* __restrict__ l1b,
                            const float* __restrict__ l2w, const float* __restrict__ l2b,
                            float* __restrict__ out) {
    __shared__ float hbar[128], tv[128], pl[128], z1[64], lg[2];
    int g = blockIdx.x, t = threadIdx.x;   // 128 threads
    int lo = 0, hi = nn;
    while (lo < hi) { int m = (lo + hi) >> 1; if (batch[m] < g) lo = m + 1; else hi = m; }
    int s0 = lo;
    lo = 0; hi = nn;
    while (lo < hi) { int m = (lo + hi) >> 1; if (batch[m] <= g) lo = m + 1; else hi = m; }
    int e0 = lo;
    float cntv = fmaxf((float)(e0 - s0), 1.0f);
    hbar[t] = poolsum[g * 128 + t] / cntv;
    __syncthreads();
    float a = attn_in_b[256 + t];
    for (int k = 0; k < 128; ++k) a += attn_in_w[(256 + t) * 128 + k] * hbar[k];
    tv[t] = a;
    __syncthreads();
    float pv = attn_out_b[t];
    for (int k = 0; k < 128; ++k) pv += attn_out_w[t * 128 + k] * tv[k];
    pl[t] = pv;
    __syncthreads();
    if (t < 64) {
        float z = l1b[t];
        for (int k = 0; k < 128; ++k) z += l1w[t * 128 + k] * pl[k];
        z1[t] = fmaxf(z, 0.0f);
    }
    __syncthreads();
    if (t < 2) {
        float lv = l2b[t];
        for (int k = 0; k < 64; ++k) lv += l2w[t * 64 + k] * z1[k];
        lg[t] = lv;
    }
    __syncthreads();
    if (t == 0) {
        float m = fmaxf(lg[0], lg[1]);
        float ls = m + logf(__expf(lg[0] - m) + __expf(lg[1] - m));
        out[g * 2 + 0] = lg[0] - ls;
        out[g * 2 + 1] = lg[1] - ls;
    }
}

// ---------------- launch ----------------
extern "C" void kernel_launch(void* const* d_in, const int* in_sizes, int n_in,
                              void* d_out, int out_size, void* d_ws, size_t ws_size,
                              hipStream_t stream) {
    const float* x          = (const float*)d_in[0];
    const int*   ei         = (const int*)d_in[1];
    const int*   batch      = (const int*)d_in[2];
    const float* w1 = (const float*)d_in[3];  const float* b1 = (const float*)d_in[4];
    const float* w2 = (const float*)d_in[5];  const float* b2 = (const float*)d_in[6];
    const float* w3 = (const float*)d_in[7];  const float* b3 = (const float*)d_in[8];
    const float* w4 = (const float*)d_in[9];  const float* b4 = (const float*)d_in[10];
    const float* wih = (const float*)d_in[11]; const float* whh = (const float*)d_in[12];
    const float* bih = (const float*)d_in[13]; const float* bhh = (const float*)d_in[14];
    const float* attn_in_w  = (const float*)d_in[15]; const float* attn_in_b  = (const float*)d_in[16];
    const float* attn_out_w = (const float*)d_in[17]; const float* attn_out_b = (const float*)d_in[18];
    const float* l1w = (const float*)d_in[19]; const float* l1b = (const float*)d_in[20];
    const float* l2w = (const float*)d_in[21]; const float* l2b = (const float*)d_in[22];
    float* out = (float*)d_out;

    char* p = (char*)d_ws;
    auto alloc = [&](size_t bytes) {
        char* r = p;
        p += (bytes + 255) & ~(size_t)255;
        return r;
    };
    int*   cnt      = (int*)alloc((size_t)N_NODES * 4);
    int*   cursor   = (int*)alloc((size_t)N_NODES * 4);
    int*   rowstart = (int*)alloc((size_t)(N_NODES + 1) * 4);
    float* dinv     = (float*)alloc((size_t)N_NODES * 4);
    int*   csr      = (int*)alloc((size_t)N_EDGES * 4);
    float* bsum     = (float*)alloc(512 * 4);
    float* poolsum  = (float*)alloc((size_t)N_GRAPH * 128 * 4);
    uint4* wfrag    = (uint4*)alloc((size_t)8192 * 16);   // 128 KB bf16 Whh frags
    float* bufA     = (float*)alloc((size_t)N_NODES * 256 * 4);
    float* bufB     = (float*)alloc((size_t)N_NODES * 256 * 4);
    float* xg       = (float*)alloc((size_t)N_NODES * 512 * 4);

    hipMemsetAsync(cnt, 0, (size_t)N_NODES * 4, stream);
    hipMemsetAsync(cursor, 0, (size_t)N_NODES * 4, stream);
    hipMemsetAsync(poolsum, 0, (size_t)N_GRAPH * 128 * 4, stream);   // empty-graph safety

    const int* srcp = ei;
    const int* dstp = ei + N_EDGES;

    int eb = (N_EDGES + 255) / 256;
    int nb = (N_NODES + 255) / 256;
    count_kernel<<<eb, 256, 0, stream>>>(dstp, cnt, N_EDGES);
    scan_kernel<<<1, 1024, 0, stream>>>(cnt, rowstart, N_NODES);
    dinv_kernel<<<nb, 256, 0, stream>>>(cnt, dinv, N_NODES);
    fill_kernel<<<eb, 256, 0, stream>>>(srcp, dstp, rowstart, cursor, csr, N_EDGES);
    wprep_kernel<<<32, 256, 0, stream>>>(whh, wfrag);

    int mg = (N_NODES + 63) / 64;   // 313
    gemm_kernel<false, false, false><<<dim3(mg, 1), 256, 0, stream>>>(x, w1, nullptr, bufA, N_NODES, 128, 64);
    agg_kernel<<<N_NODES, 64, 0, stream>>>(bufA, rowstart, csr, dinv, b1, bufB, 64);
    gemm_kernel<false, false, false><<<dim3(mg, 1), 256, 0, stream>>>(bufB, w2, nullptr, bufA, N_NODES, 64, 64);
    agg_kernel<<<N_NODES, 64, 0, stream>>>(bufA, rowstart, csr, dinv, b2, bufB, 64);
    gemm_kernel<false, false, false><<<dim3(mg, 2), 256, 0, stream>>>(bufB, w3, nullptr, bufA, N_NODES, 64, 128);
    agg_kernel<<<N_NODES, 128, 0, stream>>>(bufA, rowstart, csr, dinv, b3, bufB, 128);
    gemm_kernel<false, false, false><<<dim3(mg, 4), 256, 0, stream>>>(bufB, w4, nullptr, bufA, N_NODES, 128, 256);
    agg_kernel<<<N_NODES, 256, 0, stream>>>(bufA, rowstart, csr, dinv, b4, bufB, 256);

    // xg = h4 @ wih^T + (bih + bhh)
    vadd_kernel<<<2, 256, 0, stream>>>(bih, bhh, bsum, 512);
    gemm_kernel<true, false, true><<<dim3(mg, 8), 256, 0, stream>>>(bufB, wih, bsum, xg, N_NODES, 256, 512);

    // sequential LSTM: 8 waves, AGPR weights, lgkm-only barrier, shadowed pooling
    lstm_mfma_kernel<<<1, 512, 0, stream>>>(xg, (const uint4*)wfrag, batch, poolsum, N_NODES);

    // head
    head_kernel<<<N_GRAPH, 128, 0, stream>>>(poolsum, batch, N_NODES,
                                             attn_in_w, attn_in_b, attn_out_w, attn_out_b,
                                             l1w, l1b, l2w, l2b, out);
}

// Round 13
// 12666.241 us; speedup vs baseline: 1.3814x; 1.0481x over previous
//
#include <hip/hip_runtime.h>
#include <cstdint>
#include <cstddef>

#define N_NODES 20000
#define N_EDGES 640000
#define N_GRAPH 64

typedef __attribute__((ext_vector_type(8))) short bf16x8;
typedef __attribute__((ext_vector_type(4))) float f32x4;

// ---------------- math helpers ----------------
__device__ __forceinline__ float sigmoidf_(float x) {
    return 1.0f / (1.0f + __expf(-x));
}
__device__ __forceinline__ float tanhf_(float x) {
    float xc = fminf(fmaxf(x, -9.0f), 9.0f);
    float e = __expf(2.0f * xc);
    return (e - 1.0f) / (e + 1.0f);
}
__device__ __forceinline__ unsigned short f2bf_(float x) {
    unsigned int u = __builtin_bit_cast(unsigned int, x);
    return (unsigned short)((u + 0x7fffu + ((u >> 16) & 1u)) >> 16);
}
__device__ __forceinline__ float sel4_(f32x4 v, bool b1, bool b2) {
    float lo = b1 ? v.y : v.x;      // static regs, runtime mask -> cndmask tree
    float hi = b1 ? v.w : v.z;
    return b2 ? hi : lo;
}

// ---------------- CSR build ----------------
__global__ void count_kernel(const int* __restrict__ dst, int* __restrict__ cnt, int e) {
    int i = blockIdx.x * blockDim.x + threadIdx.x;
    if (i < e) atomicAdd(&cnt[dst[i]], 1);
}

__global__ void scan_kernel(const int* __restrict__ cnt, int* __restrict__ rowstart, int n) {
    __shared__ int buf[1024];
    __shared__ int carry_sh;
    int tid = threadIdx.x;
    if (tid == 0) carry_sh = 0;
    __syncthreads();
    for (int base = 0; base < n; base += 1024) {
        int i = base + tid;
        int v = (i < n) ? cnt[i] : 0;
        buf[tid] = v;
        __syncthreads();
        for (int off = 1; off < 1024; off <<= 1) {
            int t = (tid >= off) ? buf[tid - off] : 0;
            __syncthreads();
            buf[tid] += t;
            __syncthreads();
        }
        int carry = carry_sh;
        if (i < n) rowstart[i] = carry + buf[tid] - v;   // exclusive
        __syncthreads();
        if (tid == 1023) carry_sh = carry + buf[1023];
        __syncthreads();
    }
    if (tid == 0) rowstart[n] = carry_sh;
}

__global__ void dinv_kernel(const int* __restrict__ cnt, float* __restrict__ dinv, int n) {
    int i = blockIdx.x * blockDim.x + threadIdx.x;
    if (i < n) dinv[i] = rsqrtf((float)cnt[i] + 1.0f);   // +1 for self loop; deg >= 1
}

__global__ void fill_kernel(const int* __restrict__ src, const int* __restrict__ dst,
                            const int* __restrict__ rowstart, int* __restrict__ cursor,
                            int* __restrict__ csr_src, int e) {
    int i = blockIdx.x * blockDim.x + threadIdx.x;
    if (i < e) {
        int d = dst[i];
        int pos = rowstart[d] + atomicAdd(&cursor[d], 1);
        csr_src[pos] = src[i];
    }
}

// ---------------- tiled f32 GEMM: C[M,F] = A[M,K] * B (+bias)(relu) ----------------
template <bool BT, bool RELU, bool BIAS>
__global__ void gemm_kernel(const float* __restrict__ A, const float* __restrict__ B,
                            const float* __restrict__ bias, float* __restrict__ C,
                            int M, int K, int F) {
    __shared__ float As[16][65];
    __shared__ float Bs[16][65];
    int bm = blockIdx.x * 64;
    int bn = blockIdx.y * 64;
    int tid = threadIdx.x;                 // 256 threads
    int tm = (tid >> 4) << 2;
    int tn = (tid & 15) << 2;
    float acc[4][4] = {};
    for (int k0 = 0; k0 < K; k0 += 16) {
        {   // A tile: 64 rows x 16 k
            int idx = tid * 4;
            int m = idx >> 4;
            int kk = idx & 15;
            int gm = bm + m;
            float4 v = make_float4(0.f, 0.f, 0.f, 0.f);
            if (gm < M) v = *(const float4*)&A[(size_t)gm * K + k0 + kk];
            As[kk + 0][m] = v.x; As[kk + 1][m] = v.y; As[kk + 2][m] = v.z; As[kk + 3][m] = v.w;
        }
        if (BT) {
            int idx = tid * 4;
            int nn = idx >> 4;
            int kk = idx & 15;
            float4 v = *(const float4*)&B[(size_t)(bn + nn) * K + k0 + kk];
            Bs[kk + 0][nn] = v.x; Bs[kk + 1][nn] = v.y; Bs[kk + 2][nn] = v.z; Bs[kk + 3][nn] = v.w;
        } else {
            int idx = tid * 4;
            int kk = idx >> 6;
            int nn = idx & 63;
            float4 v = *(const float4*)&B[(size_t)(k0 + kk) * F + bn + nn];
            Bs[kk][nn + 0] = v.x; Bs[kk][nn + 1] = v.y; Bs[kk][nn + 2] = v.z; Bs[kk][nn + 3] = v.w;
        }
        __syncthreads();
#pragma unroll
        for (int kk = 0; kk < 16; ++kk) {
            float av[4], bv[4];
#pragma unroll
            for (int i = 0; i < 4; ++i) av[i] = As[kk][tm + i];
#pragma unroll
            for (int j = 0; j < 4; ++j) bv[j] = Bs[kk][tn + j];
#pragma unroll
            for (int i = 0; i < 4; ++i)
#pragma unroll
                for (int j = 0; j < 4; ++j) acc[i][j] += av[i] * bv[j];
        }
        __syncthreads();
    }
#pragma unroll
    for (int i = 0; i < 4; ++i) {
        int gm = bm + tm + i;
        if (gm >= M) continue;
#pragma unroll
        for (int j = 0; j < 4; ++j) {
            float v = acc[i][j];
            if (BIAS) v += bias[bn + tn + j];
            if (RELU) v = fmaxf(v, 0.0f);
            C[(size_t)gm * F + bn + tn + j] = v;
        }
    }
}

// ---------------- GCN aggregation ----------------
__global__ void agg_kernel(const float* __restrict__ H, const int* __restrict__ rowstart,
                           const int* __restrict__ csr_src, const float* __restrict__ dinv,
                           const float* __restrict__ bias, float* __restrict__ OUT, int F) {
    int n = blockIdx.x;
    int f = threadIdx.x;
    float di = dinv[n];
    int s = rowstart[n], e = rowstart[n + 1];
    float acc = di * H[(size_t)n * F + f];   // self loop
    for (int i = s; i < e; ++i) {
        int src = csr_src[i];
        acc += dinv[src] * H[(size_t)src * F + f];
    }
    OUT[(size_t)n * F + f] = fmaxf(bias[f] + di * acc, 0.0f);
}

__global__ void vadd_kernel(const float* __restrict__ a, const float* __restrict__ b,
                            float* __restrict__ o, int n) {
    int i = blockIdx.x * blockDim.x + threadIdx.x;
    if (i < n) o[i] = a[i] + b[i];
}

// ---------------- Whh -> bf16 fragment-order rearrange (gate-per-subtile layout) ----------------
// wave w (0..7) owns hidden units [16w,16w+16); frag i = s*4+kc, s = GATE (0=i,1=f,2=g,3=o),
// kc = k-chunk. lane l: elem j = Whh[128s + 16w + (l&15)][kc*32 + (l>>4)*8 + j]
// flat at out[(w*16+i)*64 + l].
__global__ void wprep_kernel(const float* __restrict__ whh, uint4* __restrict__ out) {
    int tau = blockIdx.x * blockDim.x + threadIdx.x;   // 0..8191
    if (tau >= 8192) return;
    int l  = tau & 63;
    int f  = (tau >> 6) & 15;
    int w  = tau >> 10;
    int s  = f >> 2, kc = f & 3;
    int grow = 128 * s + 16 * w + (l & 15);
    int kb   = kc * 32 + (l >> 4) * 8;
    const float* src = whh + (size_t)grow * 128 + kb;
    unsigned int h[8];
#pragma unroll
    for (int j = 0; j < 8; ++j) h[j] = f2bf_(src[j]);
    uint4 v;
    v.x = h[0] | (h[1] << 16);
    v.y = h[2] | (h[3] << 16);
    v.z = h[4] | (h[5] << 16);
    v.w = h[6] | (h[7] << 16);
    out[tau] = v;
}

// ---------------- LSTM: one lgkm-only barrier/step, in-register gate math ----------------
#define SF(i, A0, A1, A2, A3) { \
    uint4 q = wfr[(size_t)(w * 16 + (i)) * 64 + l]; \
    asm volatile("v_accvgpr_write_b32 a" #A0 ", %0\n\t" \
                 "v_accvgpr_write_b32 a" #A1 ", %1\n\t" \
                 "v_accvgpr_write_b32 a" #A2 ", %2\n\t" \
                 "v_accvgpr_write_b32 a" #A3 ", %3" \
                 :: "v"(q.x), "v"(q.y), "v"(q.z), "v"(q.w) \
                 : "a" #A0, "a" #A1, "a" #A2, "a" #A3); }

// One LSTM step. Consumes X0..X3 as MFMA C-in (destroyed), then reloads them with
// step N+2's xg (stays in flight ~2 iterations -- barrier below does NOT drain vmcnt).
#define LSTM_STEP(N, X0, X1, X2, X3, RD, WR) do { \
    bf16x8 b0 = *(const bf16x8*)&h_bf[RD][ 0 + lg * 8]; \
    bf16x8 b1 = *(const bf16x8*)&h_bf[RD][32 + lg * 8]; \
    bf16x8 b2 = *(const bf16x8*)&h_bf[RD][64 + lg * 8]; \
    bf16x8 b3 = *(const bf16x8*)&h_bf[RD][96 + lg * 8]; \
    asm volatile( \
        "s_nop 1\n\t" \
        "v_mfma_f32_16x16x32_bf16 %0, a[0:3],   %4, %0\n\t" \
        "v_mfma_f32_16x16x32_bf16 %1, a[16:19], %4, %1\n\t" \
        "v_mfma_f32_16x16x32_bf16 %2, a[32:35], %4, %2\n\t" \
        "v_mfma_f32_16x16x32_bf16 %3, a[48:51], %4, %3" \
        : "+v"(X0), "+v"(X1), "+v"(X2), "+v"(X3) : "v"(b0)); \
    asm volatile( \
        "v_mfma_f32_16x16x32_bf16 %0, a[4:7],   %4, %0\n\t" \
        "v_mfma_f32_16x16x32_bf16 %1, a[20:23], %4, %1\n\t" \
        "v_mfma_f32_16x16x32_bf16 %2, a[36:39], %4, %2\n\t" \
        "v_mfma_f32_16x16x32_bf16 %3, a[52:55], %4, %3" \
        : "+v"(X0), "+v"(X1), "+v"(X2), "+v"(X3) : "v"(b1)); \
    asm volatile( \
        "v_mfma_f32_16x16x32_bf16 %0, a[8:11],  %4, %0\n\t" \
        "v_mfma_f32_16x16x32_bf16 %1, a[24:27], %4, %1\n\t" \
        "v_mfma_f32_16x16x32_bf16 %2, a[40:43], %4, %2\n\t" \
        "v_mfma_f32_16x16x32_bf16 %3, a[56:59], %4, %3" \
        : "+v"(X0), "+v"(X1), "+v"(X2), "+v"(X3) : "v"(b2)); \
    asm volatile( \
        "v_mfma_f32_16x16x32_bf16 %0, a[12:15], %4, %0\n\t" \
        "v_mfma_f32_16x16x32_bf16 %1, a[28:31], %4, %1\n\t" \
        "v_mfma_f32_16x16x32_bf16 %2, a[44:47], %4, %2\n\t" \
        "v_mfma_f32_16x16x32_bf16 %3, a[60:63], %4, %3\n\t" \
        "s_nop 7\n\t" \
        "s_nop 7" \
        : "+v"(X0), "+v"(X1), "+v"(X2), "+v"(X3) : "v"(b3)); \
    /* every lane holds gates i,f,g,o for units 16w+4lg+{0..3}; pick unit r=l&3 */ \
    float gi = sel4_(X0, s1m, s2m); \
    float gf = sel4_(X1, s1m, s2m); \
    float gG = sel4_(X2, s1m, s2m); \
    float go = sel4_(X3, s1m, s2m); \
    { int np = ((N) + 2 < steps) ? (N) + 2 : (N); \
      const float* xp = xg + (size_t)np * 512 + xoff; \
      X0 = *(const f32x4*)(xp); \
      X1 = *(const f32x4*)(xp + 128); \
      X2 = *(const f32x4*)(xp + 256); \
      X3 = *(const f32x4*)(xp + 384); } \
    float iv = sigmoidf_(gi); \
    float fv = sigmoidf_(gf); \
    float gv = tanhf_(gG); \
    float ov = sigmoidf_(go); \
    c = fv * c + iv * gv; \
    float hn = ov * tanhf_(c); \
    if (wrlane) h_bf[WR][uidx] = f2bf_(hn); \
    while ((N) == bnext) { \
        if (wrlane) poolsum[gidx * 128 + uidx] = pacc; \
        pacc = 0.0f; ++gidx; bnext = bnd_s[gidx + 1]; \
    } \
    pacc += hn; \
    asm volatile("s_waitcnt lgkmcnt(0)\n\ts_barrier" ::: "memory"); \
} while (0)

__global__ __launch_bounds__(512)
__attribute__((amdgpu_waves_per_eu(2, 2)))
void lstm_mfma_kernel(const float* __restrict__ xg, const uint4* __restrict__ wfr,
                      const int* __restrict__ batch, float* __restrict__ poolsum, int steps) {
    __shared__ __align__(16) unsigned short h_bf[2][128];
    __shared__ int bnd_s[65];
    const int t = threadIdx.x;
    const int w = t >> 6;                 // wave 0..7 -> hidden units [16w, 16w+16)
    const int l = t & 63;
    const int lg = l >> 4;
    const bool s1m = (l & 1) != 0;
    const bool s2m = (l & 2) != 0;
    const bool wrlane = (l & 15) < 4;     // 16 writer lanes per wave
    const int uidx = 16 * w + 4 * lg + (l & 3);   // this lane's hidden unit
    const int xoff = 16 * w + 4 * lg;

    // stage Whh into AGPRs once
    SF(0, 0, 1, 2, 3)     SF(1, 4, 5, 6, 7)     SF(2, 8, 9, 10, 11)    SF(3, 12, 13, 14, 15)
    SF(4, 16, 17, 18, 19) SF(5, 20, 21, 22, 23) SF(6, 24, 25, 26, 27)  SF(7, 28, 29, 30, 31)
    SF(8, 32, 33, 34, 35) SF(9, 36, 37, 38, 39) SF(10, 40, 41, 42, 43) SF(11, 44, 45, 46, 47)
    SF(12, 48, 49, 50, 51) SF(13, 52, 53, 54, 55) SF(14, 56, 57, 58, 59) SF(15, 60, 61, 62, 63)

    if (t < 128) h_bf[0][t] = 0;
    if (t <= 64) {                         // one-time graph-boundary table
        int lo = 0, hi = steps;
        while (lo < hi) { int m = (lo + hi) >> 1; if (batch[m] < t) lo = m + 1; else hi = m; }
        bnd_s[t] = lo;
    }
    float c = 0.0f, pacc = 0.0f;

    // 2-deep xg pipeline: xa = step 0, xb = step 1
    const float* x0p = xg + xoff;
    f32x4 xa0 = *(const f32x4*)(x0p);
    f32x4 xa1 = *(const f32x4*)(x0p + 128);
    f32x4 xa2 = *(const f32x4*)(x0p + 256);
    f32x4 xa3 = *(const f32x4*)(x0p + 384);
    const float* x1p = xg + 512 + xoff;
    f32x4 xb0 = *(const f32x4*)(x1p);
    f32x4 xb1 = *(const f32x4*)(x1p + 128);
    f32x4 xb2 = *(const f32x4*)(x1p + 256);
    f32x4 xb3 = *(const f32x4*)(x1p + 384);
    __syncthreads();                       // init barrier (full drain OK, once)
    int gidx = 0, bnext = bnd_s[1];

    for (int n = 0; n < steps; n += 2) {   // steps even (20000)
        LSTM_STEP(n,     xa0, xa1, xa2, xa3, 0, 1);
        LSTM_STEP(n + 1, xb0, xb1, xb2, xb3, 1, 0);
    }
    if (wrlane) poolsum[gidx * 128 + uidx] = pacc;
}

// ---------------- head (computes counts itself via binary search) ----------------
__global__ void head_kernel(const float* __restrict__ poolsum, const int* __restrict__ batch,
                            int nn,
                            const float* __restrict__ attn_in_w, const float* __restrict__ attn_in_b,
                            const float* __restrict__ attn_out_w, const float* __restrict__ attn_out_b,
                            const float* __restrict__ l1w, const float* __restrict__ l1b,
                            const float* __restrict__ l2w, const float* __restrict__ l2b,
                            float* __restrict__ out) {
    __shared__ float hbar[128], tv[128], pl[128], z1[64], lg[2];
    int g = blockIdx.x, t = threadIdx.x;   // 128 threads
    int lo = 0, hi = nn;
    while (lo < hi) { int m = (lo + hi) >> 1; if (batch[m] < g) lo = m + 1; else hi = m; }
    int s0 = lo;
    lo = 0; hi = nn;
    while (lo < hi) { int m = (lo + hi) >> 1; if (batch[m] <= g) lo = m + 1; else hi = m; }
    int e0 = lo;
    float cntv = fmaxf((float)(e0 - s0), 1.0f);
    hbar[t] = poolsum[g * 128 + t] / cntv;
    __syncthreads();
    float a = attn_in_b[256 + t];
    for (int k = 0; k < 128; ++k) a += attn_in_w[(256 + t) * 128 + k] * hbar[k];
    tv[t] = a;
    __syncthreads();
    float pv = attn_out_b[t];
    for (int k = 0; k < 128; ++k) pv += attn_out_w[t * 128 + k] * tv[k];
    pl[t] = pv;
    __syncthreads();
    if (t < 64) {
        float z = l1b[t];
        for (int k = 0; k < 128; ++k) z += l1w[t * 128 + k] * pl[k];
        z1[t] = fmaxf(z, 0.0f);
    }
    __syncthreads();
    if (t < 2) {
        float lv = l2b[t];
        for (int k = 0; k < 64; ++k) lv += l2w[t * 64 + k] * z1[k];
        lg[t] = lv;
    }
    __syncthreads();
    if (t == 0) {
        float m = fmaxf(lg[0], lg[1]);
        float ls = m + logf(__expf(lg[0] - m) + __expf(lg[1] - m));
        out[g * 2 + 0] = lg[0] - ls;
        out[g * 2 + 1] = lg[1] - ls;
    }
}

// ---------------- launch ----------------
extern "C" void kernel_launch(void* const* d_in, const int* in_sizes, int n_in,
                              void* d_out, int out_size, void* d_ws, size_t ws_size,
                              hipStream_t stream) {
    const float* x          = (const float*)d_in[0];
    const int*   ei         = (const int*)d_in[1];
    const int*   batch      = (const int*)d_in[2];
    const float* w1 = (const float*)d_in[3];  const float* b1 = (const float*)d_in[4];
    const float* w2 = (const float*)d_in[5];  const float* b2 = (const float*)d_in[6];
    const float* w3 = (const float*)d_in[7];  const float* b3 = (const float*)d_in[8];
    const float* w4 = (const float*)d_in[9];  const float* b4 = (const float*)d_in[10];
    const float* wih = (const float*)d_in[11]; const float* whh = (const float*)d_in[12];
    const float* bih = (const float*)d_in[13]; const float* bhh = (const float*)d_in[14];
    const float* attn_in_w  = (const float*)d_in[15]; const float* attn_in_b  = (const float*)d_in[16];
    const float* attn_out_w = (const float*)d_in[17]; const float* attn_out_b = (const float*)d_in[18];
    const float* l1w = (const float*)d_in[19]; const float* l1b = (const float*)d_in[20];
    const float* l2w = (const float*)d_in[21]; const float* l2b = (const float*)d_in[22];
    float* out = (float*)d_out;

    char* p = (char*)d_ws;
    auto alloc = [&](size_t bytes) {
        char* r = p;
        p += (bytes + 255) & ~(size_t)255;
        return r;
    };
    int*   cnt      = (int*)alloc((size_t)N_NODES * 4);
    int*   cursor   = (int*)alloc((size_t)N_NODES * 4);
    int*   rowstart = (int*)alloc((size_t)(N_NODES + 1) * 4);
    float* dinv     = (float*)alloc((size_t)N_NODES * 4);
    int*   csr      = (int*)alloc((size_t)N_EDGES * 4);
    float* bsum     = (float*)alloc(512 * 4);
    float* poolsum  = (float*)alloc((size_t)N_GRAPH * 128 * 4);
    uint4* wfrag    = (uint4*)alloc((size_t)8192 * 16);   // 128 KB bf16 Whh frags
    float* bufA     = (float*)alloc((size_t)N_NODES * 256 * 4);
    float* bufB     = (float*)alloc((size_t)N_NODES * 256 * 4);
    float* xg       = (float*)alloc((size_t)N_NODES * 512 * 4);

    hipMemsetAsync(cnt, 0, (size_t)N_NODES * 4, stream);
    hipMemsetAsync(cursor, 0, (size_t)N_NODES * 4, stream);
    hipMemsetAsync(poolsum, 0, (size_t)N_GRAPH * 128 * 4, stream);   // empty-graph safety

    const int* srcp = ei;
    const int* dstp = ei + N_EDGES;

    int eb = (N_EDGES + 255) / 256;
    int nb = (N_NODES + 255) / 256;
    count_kernel<<<eb, 256, 0, stream>>>(dstp, cnt, N_EDGES);
    scan_kernel<<<1, 1024, 0, stream>>>(cnt, rowstart, N_NODES);
    dinv_kernel<<<nb, 256, 0, stream>>>(cnt, dinv, N_NODES);
    fill_kernel<<<eb, 256, 0, stream>>>(srcp, dstp, rowstart, cursor, csr, N_EDGES);
    wprep_kernel<<<32, 256, 0, stream>>>(whh, wfrag);

    int mg = (N_NODES + 63) / 64;   // 313
    gemm_kernel<false, false, false><<<dim3(mg, 1), 256, 0, stream>>>(x, w1, nullptr, bufA, N_NODES, 128, 64);
    agg_kernel<<<N_NODES, 64, 0, stream>>>(bufA, rowstart, csr, dinv, b1, bufB, 64);
    gemm_kernel<false, false, false><<<dim3(mg, 1), 256, 0, stream>>>(bufB, w2, nullptr, bufA, N_NODES, 64, 64);
    agg_kernel<<<N_NODES, 64, 0, stream>>>(bufA, rowstart, csr, dinv, b2, bufB, 64);
    gemm_kernel<false, false, false><<<dim3(mg, 2), 256, 0, stream>>>(bufB, w3, nullptr, bufA, N_NODES, 64, 128);
    agg_kernel<<<N_NODES, 128, 0, stream>>>(bufA, rowstart, csr, dinv, b3, bufB, 128);
    gemm_kernel<false, false, false><<<dim3(mg, 4), 256, 0, stream>>>(bufB, w4, nullptr, bufA, N_NODES, 128, 256);
    agg_kernel<<<N_NODES, 256, 0, stream>>>(bufA, rowstart, csr, dinv, b4, bufB, 256);

    // xg = h4 @ wih^T + (bih + bhh)
    vadd_kernel<<<2, 256, 0, stream>>>(bih, bhh, bsum, 512);
    gemm_kernel<true, false, true><<<dim3(mg, 8), 256, 0, stream>>>(bufB, wih, bsum, xg, N_NODES, 256, 512);

    // sequential LSTM: asm-MFMA, AGPR weights, 1 lgkm-only barrier/step, in-register gates
    lstm_mfma_kernel<<<1, 512, 0, stream>>>(xg, (const uint4*)wfrag, batch, poolsum, N_NODES);

    // head
    head_kernel<<<N_GRAPH, 128, 0, stream>>>(poolsum, batch, N_NODES,
                                             attn_in_w, attn_in_b, attn_out_w, attn_out_b,
                                             l1w, l1b, l2w, l2b, out);
}